// Round 13
// baseline (877.245 us; speedup 1.0000x reference)
//
#include <hip/hip_runtime.h>

#define B_ 2
#define S_ 2048
#define D_ 2048
#define H_ 16
#define NOPE_ 128
#define ROPE_ 64
#define V_ 128
#define C_ 512
#define QK_ 192   // NOPE+ROPE
#define CR_ 576   // C+ROPE
#define BS_ 4096  // B*S

typedef unsigned short ushort_t;
typedef unsigned int uint_t;
typedef __attribute__((ext_vector_type(8))) short bf16x8;
typedef __attribute__((ext_vector_type(4))) float f32x4;

// async global->LDS, 16B per lane. LDS dest = wave-uniform base + lane*16.
#define GLD16(gp, lp) __builtin_amdgcn_global_load_lds( \
    (const __attribute__((address_space(1))) void*)(gp), \
    (__attribute__((address_space(3))) void*)(lp), 16, 0, 0)

__device__ __forceinline__ float us2f(ushort_t u) {
    unsigned int x = ((unsigned int)u) << 16;
    return __uint_as_float(x);
}
__device__ __forceinline__ ushort_t f2us(float f) {
    unsigned int x = __float_as_uint(f);
    unsigned int r = (x + 0x7fffu + ((x >> 16) & 1u)) >> 16;
    return (ushort_t)r;
}

// ---------- merged f32 -> bf16 conversions (one launch) ----------
__global__ __launch_bounds__(256) void conv_all_k(
    const float* __restrict__ x,    ushort_t* __restrict__ xb,
    const float* __restrict__ wq,   ushort_t* __restrict__ wqb,
    const float* __restrict__ wo,   ushort_t* __restrict__ wob,
    const float* __restrict__ wkva, ushort_t* __restrict__ wkvab,
    const float* __restrict__ wkvb, ushort_t* __restrict__ wvb)
{
    int bid = blockIdx.x;
    if (bid < 8192) {
        long long i = ((long long)bid * 256 + threadIdx.x) * 4;
        float4 v = *reinterpret_cast<const float4*>(x + i);
        ushort4 o; o.x = f2us(v.x); o.y = f2us(v.y); o.z = f2us(v.z); o.w = f2us(v.w);
        *reinterpret_cast<ushort4*>(xb + i) = o;
    } else if (bid < 14336) {
        long long i = ((long long)(bid - 8192) * 256 + threadIdx.x) * 4;
        float4 v = *reinterpret_cast<const float4*>(wq + i);
        ushort4 o; o.x = f2us(v.x); o.y = f2us(v.y); o.z = f2us(v.z); o.w = f2us(v.w);
        *reinterpret_cast<ushort4*>(wqb + i) = o;
    } else if (bid < 18432) {
        long long i = ((long long)(bid - 14336) * 256 + threadIdx.x) * 4;
        float4 v = *reinterpret_cast<const float4*>(wo + i);
        ushort4 o; o.x = f2us(v.x); o.y = f2us(v.y); o.z = f2us(v.z); o.w = f2us(v.w);
        *reinterpret_cast<ushort4*>(wob + i) = o;
    } else if (bid < 19712) {
        long long i = ((long long)(bid - 18432) * 256 + threadIdx.x) * 4;
        int row = (int)(i >> 11);
        ushort4 o;
        if (row < 576) {
            float4 v = *reinterpret_cast<const float4*>(wkva + i);
            o.x = f2us(v.x); o.y = f2us(v.y); o.z = f2us(v.z); o.w = f2us(v.w);
        } else { o.x = o.y = o.z = o.w = 0; }
        *reinterpret_cast<ushort4*>(wkvab + i) = o;
    } else {
        long long i = ((long long)(bid - 19712) * 256 + threadIdx.x) * 4;
        int h = (int)(i >> 16);
        int rem = (int)(i & 65535);
        float4 v = *reinterpret_cast<const float4*>(wkvb + (long long)h * 131072 + 65536 + rem);
        ushort4 o; o.x = f2us(v.x); o.y = f2us(v.y); o.z = f2us(v.z); o.w = f2us(v.w);
        *reinterpret_cast<ushort4*>(wvb + i) = o;
    }
}

// w_nope (per h: rows 0..127 of 256x512) -> wnT [h][512][128] bf16 (transposed)
__global__ __launch_bounds__(256) void conv_wnt_k(
    const float* __restrict__ wkvb, ushort_t* __restrict__ wnT)
{
    __shared__ float st[32][33];
    int h = blockIdx.z;
    int d0 = blockIdx.x * 32, c0 = blockIdx.y * 32;
    int t = threadIdx.x;
    int dl = t >> 3, c4 = (t & 7) * 4;
    float4 v = *reinterpret_cast<const float4*>(
        wkvb + (long long)h * 131072 + (d0 + dl) * 512 + c0 + c4);
    st[dl][c4] = v.x; st[dl][c4+1] = v.y; st[dl][c4+2] = v.z; st[dl][c4+3] = v.w;
    __syncthreads();
    int cl = t >> 3, d4 = (t & 7) * 4;
    ushort4 o;
    o.x = f2us(st[d4][cl]);   o.y = f2us(st[d4+1][cl]);
    o.z = f2us(st[d4+2][cl]); o.w = f2us(st[d4+3][cl]);
    *reinterpret_cast<ushort4*>(wnT + (long long)h * 65536 + (c0 + cl) * 128 + d0 + d4) = o;
}

// ---------- MFMA GEMM (m97 structure) ----------
template <typename TC, bool NGUARD>
__global__ __launch_bounds__(256) void gemm_mfma_k(
    const ushort_t* __restrict__ A, int lda, long long strideAz,
    const ushort_t* __restrict__ Bm, int ldb, long long strideBz,
    TC* __restrict__ Cm, int ldc, long long strideCz,
    int K, int N_real)
{
    __shared__ ushort_t sA[128 * 32];
    __shared__ ushort_t sB[128 * 32];
    const int tid = threadIdx.x;
    const int w = tid >> 6, ln = tid & 63;
    const int g = ln >> 4, r16 = ln & 15;
    const int wr = w >> 1, wc = w & 1;
    const int z = blockIdx.z;
    A  += (long long)z * strideAz;
    Bm += (long long)z * strideBz;
    Cm += (long long)z * strideCz;
    const long long m0 = (long long)blockIdx.y * 128;
    const long long n0 = (long long)blockIdx.x * 128;

    const int r0 = tid >> 2, kc8 = (tid & 3) * 8;
    const ushort_t* a0 = A + (m0 + r0) * lda + kc8;
    const ushort_t* a1 = A + (m0 + 64 + r0) * lda + kc8;
    const ushort_t* b0 = Bm + (n0 + r0) * ldb + kc8;
    const ushort_t* b1 = Bm + (n0 + 64 + r0) * ldb + kc8;
    ushort_t* sA0 = sA + w * 512;
    ushort_t* sA1 = sA + 2048 + w * 512;
    ushort_t* sB0 = sB + w * 512;
    ushort_t* sB1 = sB + 2048 + w * 512;

    const f32x4 zero4 = {0.f, 0.f, 0.f, 0.f};
    f32x4 acc[4][4];
    #pragma unroll
    for (int i = 0; i < 4; ++i)
        #pragma unroll
        for (int j = 0; j < 4; ++j) acc[i][j] = zero4;

    for (int k0 = 0; k0 < K; k0 += 32) {
        GLD16(a0 + k0, sA0);
        GLD16(a1 + k0, sA1);
        GLD16(b0 + k0, sB0);
        GLD16(b1 + k0, sB1);
        __syncthreads();
        bf16x8 af[4], bfr[4];
        #pragma unroll
        for (int i = 0; i < 4; ++i)
            af[i] = *reinterpret_cast<const bf16x8*>(&sA[(64 * wr + 16 * i + r16) * 32 + 8 * g]);
        #pragma unroll
        for (int j = 0; j < 4; ++j)
            bfr[j] = *reinterpret_cast<const bf16x8*>(&sB[(64 * wc + 16 * j + r16) * 32 + 8 * g]);
        __builtin_amdgcn_s_setprio(1);
        #pragma unroll
        for (int i = 0; i < 4; ++i)
            #pragma unroll
            for (int j = 0; j < 4; ++j)
                acc[i][j] = __builtin_amdgcn_mfma_f32_16x16x32_bf16(af[i], bfr[j], acc[i][j], 0, 0, 0);
        __builtin_amdgcn_s_setprio(0);
        __syncthreads();
    }
    #pragma unroll
    for (int i = 0; i < 4; ++i) {
        #pragma unroll
        for (int j = 0; j < 4; ++j) {
            int nn = (int)n0 + 64 * wc + 16 * j + r16;
            if (NGUARD && nn >= N_real) continue;
            #pragma unroll
            for (int r = 0; r < 4; ++r) {
                long long row = m0 + 64 * wr + 16 * i + 4 * g + r;
                float v = acc[i][j][r];
                if constexpr (sizeof(TC) == 2) Cm[row * ldc + nn] = (TC)f2us(v);
                else                           Cm[row * ldc + nn] = (TC)v;
            }
        }
    }
}

// ---------- RoPE on q_pe ----------
__global__ __launch_bounds__(256) void rope_q_k(
    const ushort_t* __restrict__ qb, ushort_t* __restrict__ qcat,
    const float* __restrict__ fc, const float* __restrict__ fs)
{
    int id = blockIdx.x * 256 + threadIdx.x;
    int i  = id & 31;
    int h  = (id >> 5) & 15;
    int bs = id >> 9;
    int s  = bs & (S_ - 1);
    float c  = fc[s * 32 + i];
    float sn = fs[s * 32 + i];
    uint_t w2 = *reinterpret_cast<const uint_t*>(
        qb + (long long)bs * 3072 + h * QK_ + NOPE_ + 2 * i);
    float tr = us2f((ushort_t)(w2 & 0xffffu));
    float ti = us2f((ushort_t)(w2 >> 16));
    float orr = tr * c - ti * sn;
    float oii = tr * sn + ti * c;
    uint_t wrd = (uint_t)f2us(orr) | ((uint_t)f2us(oii) << 16);
    ((uint_t*)qcat)[((long long)h * BS_ + bs) * 288 + 256 + i] = wrd;
}

// ---------- kv post ----------
__global__ __launch_bounds__(256) void kvpost_k(
    const float* __restrict__ kv, ushort_t* __restrict__ kvb16,
    const float* __restrict__ fc, const float* __restrict__ fs)
{
    int bs = blockIdx.x;
    const float* row = kv + (long long)bs * CR_;
    ushort_t* orow = kvb16 + (long long)bs * CR_;
    int tid = threadIdx.x;
    float v0 = row[tid], v1 = row[tid + 256];
    float ss = v0 * v0 + v1 * v1;
    #pragma unroll
    for (int m = 1; m < 64; m <<= 1) ss += __shfl_xor(ss, m, 64);
    __shared__ float red[4];
    if ((tid & 63) == 0) red[tid >> 6] = ss;
    __syncthreads();
    float tot = red[0] + red[1] + red[2] + red[3];
    float r = rsqrtf(tot * (1.0f / (float)C_) + 1e-6f);
    orow[tid] = f2us(v0 * r);
    orow[tid + 256] = f2us(v1 * r);
    if (tid < 32) {
        int s = bs & (S_ - 1);
        float c  = fc[s * 32 + tid];
        float sn = fs[s * 32 + tid];
        float tr = row[C_ + 2 * tid], ti = row[C_ + 2 * tid + 1];
        orow[C_ + 2 * tid]     = f2us(tr * c - ti * sn);
        orow[C_ + 2 * tid + 1] = f2us(tr * sn + ti * c);
    }
}

// ---------- transpose c-part of kvb16 -> vT16 [B][512][2048] ----------
__global__ __launch_bounds__(256) void vtrans_k(
    const ushort_t* __restrict__ kvb16, ushort_t* __restrict__ vT16)
{
    __shared__ ushort_t st[32][36];
    int b = blockIdx.z;
    int s0 = blockIdx.x * 32, c0 = blockIdx.y * 32;
    int t = threadIdx.x;
    int sl = t >> 3, c4 = (t & 7) * 4;
    ushort4 v = *reinterpret_cast<const ushort4*>(
        kvb16 + ((long long)(b * S_ + s0 + sl)) * CR_ + c0 + c4);
    st[sl][c4] = v.x; st[sl][c4+1] = v.y; st[sl][c4+2] = v.z; st[sl][c4+3] = v.w;
    __syncthreads();
    int cl = t >> 3, s4 = (t & 7) * 4;
    ushort4 o;
    o.x = st[s4][cl]; o.y = st[s4+1][cl]; o.z = st[s4+2][cl]; o.w = st[s4+3][cl];
    *reinterpret_cast<ushort4*>(
        vT16 + ((long long)b * 512 + c0 + cl) * 2048 + s0 + s4) = o;
}

// ---------- MFMA flash attention: 8 waves, QB=128, c-split PV via shared P (R8b) ----------
__global__ __launch_bounds__(512, 2) void attn_mfma_k(
    const ushort_t* __restrict__ qcat,   // [H][BS][576] bf16
    const ushort_t* __restrict__ kvb16,  // [BS][576] bf16
    const ushort_t* __restrict__ vT16,   // [B][512][2048] bf16
    ushort_t* __restrict__ outc)         // [BS][H*512] bf16
{
    __shared__ ushort_t sKV[2 * 32 * 576];   // XOR-swizzled 16B chunks (low3 ^ row)
    __shared__ ushort_t sVT[2 * 512 * 32];   // line-pair chunk-XOR swizzle
    __shared__ ushort_t sP[128][40];         // P^T, pitch 40 ushorts
    __shared__ float sFacS[128];
    __shared__ float sLS[128];

    const int tid = threadIdx.x;
    const int w   = tid >> 6;          // 0..7
    const int ln  = tid & 63;
    const int g   = ln >> 4;
    const int r16 = ln & 15;
    const int bh = blockIdx.y;
    const int b = bh >> 4, h = bh & 15;
    const int s0 = blockIdx.x * 128;

    // staging source offsets (inverse-swizzled), 512-thread partition
    int kvoff[4], kvoff4 = 0;
    #pragma unroll
    for (int i = 0; i < 4; ++i) {
        int p = i * 512 + tid;          // 16B-chunk 0..2047
        int row = p / 72, cs = p - row * 72;
        kvoff[i] = row * 576 + ((cs & ~7) | ((cs ^ row) & 7)) * 8;
    }
    if (w < 4) {
        int p = 2048 + tid;             // chunk 2048..2303
        int row = p / 72, cs = p - row * 72;
        kvoff4 = row * 576 + ((cs & ~7) | ((cs ^ row) & 7)) * 8;
    }
    int vtoff[4];
    #pragma unroll
    for (int i = 0; i < 4; ++i) {
        int p = i * 512 + tid;          // chunk 0..2047
        int rp = p >> 3, sw = p & 7;
        int lg = sw ^ (rp & 7);
        vtoff[i] = (2 * rp + (lg >> 2)) * 2048 + (lg & 3) * 8;
    }

    // Q fragments (B-operand: col=l&15=q-row, k=8g+j); wave w owns q rows s0+16w..+15
    bf16x8 qfrag[18];
    {
        const ushort_t* qp = qcat
            + ((long long)h * BS_ + (long long)b * S_ + (s0 + 16 * w + r16)) * 576 + 8 * g;
        #pragma unroll
        for (int kt = 0; kt < 18; ++kt)
            qfrag[kt] = *reinterpret_cast<const bf16x8*>(qp + 32 * kt);
    }

    const f32x4 zero4 = {0.f, 0.f, 0.f, 0.f};
    f32x4 acc[4][8];                    // [ct][qg]: c = 64w+16ct+4g+reg, q = 16qg+r16
    #pragma unroll
    for (int i = 0; i < 4; ++i)
        #pragma unroll
        for (int j = 0; j < 8; ++j) acc[i][j] = zero4;

    float m_run = -1e30f, l_run = 0.0f;
    const float scale = 0.0721687836487032f;  // 192^-0.5

    const ushort_t* kvsrc = kvb16 + (long long)b * S_ * 576;
    const ushort_t* vtsrc = vT16 + (long long)b * 512 * 2048;
    char* skvb = (char*)sKV;
    char* svtb = (char*)sVT;

#define STAGE_TILE(T0, DB) do { \
        const ushort_t* kvt_ = kvsrc + (long long)(T0) * 576; \
        const ushort_t* vtt_ = vtsrc + (T0); \
        _Pragma("unroll") \
        for (int i_ = 0; i_ < 4; ++i_) \
            GLD16(kvt_ + kvoff[i_], skvb + (DB) * 36864 + i_ * 8192 + w * 1024); \
        if (w < 4) GLD16(kvt_ + kvoff4, skvb + (DB) * 36864 + 32768 + w * 1024); \
        _Pragma("unroll") \
        for (int i_ = 0; i_ < 4; ++i_) \
            GLD16(vtt_ + vtoff[i_], svtb + (DB) * 32768 + i_ * 8192 + w * 1024); \
    } while (0)

    STAGE_TILE(0, 0);   // prologue

    for (int t = 0; t < 64; ++t) {
        const int cur = t & 1;
        asm volatile("s_waitcnt vmcnt(0)" ::: "memory");   // own share of tile t landed
        __builtin_amdgcn_s_barrier();                       // all landed; sP(t-1) consumed
        __builtin_amdgcn_sched_barrier(0);
        if (t < 63) STAGE_TILE((t + 1) * 32, cur ^ 1);

        // scores^T = mfma(A=KV rows, B=Q): 4 chains of 9
        const int kvb = cur * 18432;
        f32x4 d0a = zero4, d0b = zero4, d1a = zero4, d1b = zero4;
        __builtin_amdgcn_s_setprio(1);
        #pragma unroll
        for (int kt = 0; kt < 9; ++kt) {
            int ch = kt * 4 + g;
            int chs = (ch & ~7) | ((ch ^ r16) & 7);
            bf16x8 a0 = *reinterpret_cast<const bf16x8*>(&sKV[kvb + r16 * 576 + chs * 8]);
            bf16x8 a1 = *reinterpret_cast<const bf16x8*>(&sKV[kvb + (16 + r16) * 576 + chs * 8]);
            d0a = __builtin_amdgcn_mfma_f32_16x16x32_bf16(a0, qfrag[kt], d0a, 0, 0, 0);
            d1a = __builtin_amdgcn_mfma_f32_16x16x32_bf16(a1, qfrag[kt], d1a, 0, 0, 0);
        }
        #pragma unroll
        for (int kt = 9; kt < 18; ++kt) {
            int ch = kt * 4 + g;
            int chs = (ch & ~7) | ((ch ^ r16) & 7);
            bf16x8 a0 = *reinterpret_cast<const bf16x8*>(&sKV[kvb + r16 * 576 + chs * 8]);
            bf16x8 a1 = *reinterpret_cast<const bf16x8*>(&sKV[kvb + (16 + r16) * 576 + chs * 8]);
            d0b = __builtin_amdgcn_mfma_f32_16x16x32_bf16(a0, qfrag[kt], d0b, 0, 0, 0);
            d1b = __builtin_amdgcn_mfma_f32_16x16x32_bf16(a1, qfrag[kt], d1b, 0, 0, 0);
        }
        __builtin_amdgcn_s_setprio(0);
        f32x4 d0 = d0a + d0b, d1 = d1a + d1b;

        // lane-local online softmax (lane owns q-row 16w+r16; t spread over 4 g-groups)
        float p[8];
        #pragma unroll
        for (int i = 0; i < 4; ++i) { p[i] = d0[i] * scale; p[4 + i] = d1[i] * scale; }
        float mt = p[0];
        #pragma unroll
        for (int i = 1; i < 8; ++i) mt = fmaxf(mt, p[i]);
        mt = fmaxf(mt, __shfl_xor(mt, 16, 64));
        mt = fmaxf(mt, __shfl_xor(mt, 32, 64));
        bool anyneed = __any(mt > m_run + 8.0f);   // defer-max THR=8 (wave-local)
        float m_new = anyneed ? fmaxf(m_run, mt) : m_run;
        float fac = anyneed ? __expf(m_run - m_new) : 1.0f;
        m_run = m_new;
        float lt = 0.f;
        #pragma unroll
        for (int i = 0; i < 8; ++i) { p[i] = __expf(p[i] - m_new); lt += p[i]; }
        lt += __shfl_xor(lt, 16, 64);
        lt += __shfl_xor(lt, 32, 64);
        l_run = l_run * fac + lt;

        // publish P^T row (r = 16w+r16) + fac  (R8-verified mapping, pitch 40)
        {
            int r = 16 * w + r16;
            uint_t* prow = reinterpret_cast<uint_t*>(&sP[r][0]);
            #pragma unroll
            for (int tt = 0; tt < 2; ++tt)
                #pragma unroll
                for (int pr = 0; pr < 2; ++pr) {
                    uint_t wrd = (uint_t)f2us(p[tt * 4 + 2 * pr])
                               | ((uint_t)f2us(p[tt * 4 + 2 * pr + 1]) << 16);
                    prow[tt * 8 + g * 2 + pr] = wrd;
                }
            if (g == 0) sFacS[r] = fac;
        }
        asm volatile("s_waitcnt lgkmcnt(0)" ::: "memory");
        __builtin_amdgcn_s_barrier();            // sP/sFacS visible
        __builtin_amdgcn_sched_barrier(0);

        // PV c-split: wave owns c in [64w, 64w+64); always-rescale (fac==1 exact)
        const int vtb = cur * 16384;
        bf16x8 aVs[4];
        #pragma unroll
        for (int ct = 0; ct < 4; ++ct) {
            int c = 64 * w + 16 * ct + r16;
            int sw = ((c & 1) * 4 + g) ^ ((c >> 1) & 7);
            aVs[ct] = *reinterpret_cast<const bf16x8*>(&sVT[vtb + (c >> 1) * 64 + sw * 8]);
        }
        __builtin_amdgcn_s_setprio(1);
        #pragma unroll
        for (int qg = 0; qg < 8; ++qg) {
            float fv = sFacS[16 * qg + r16];
            bf16x8 pB = *reinterpret_cast<const bf16x8*>(&sP[16 * qg + r16][8 * g]);
            #pragma unroll
            for (int ct = 0; ct < 4; ++ct) {
                acc[ct][qg][0] *= fv; acc[ct][qg][1] *= fv;
                acc[ct][qg][2] *= fv; acc[ct][qg][3] *= fv;
            }
            #pragma unroll
            for (int ct = 0; ct < 4; ++ct)
                acc[ct][qg] = __builtin_amdgcn_mfma_f32_16x16x32_bf16(aVs[ct], pB, acc[ct][qg], 0, 0, 0);
        }
        __builtin_amdgcn_s_setprio(0);
    }
#undef STAGE_TILE

    // finalize: l per q via LDS, normalize, write out^T (R8-verified)
    if (g == 0) sLS[16 * w + r16] = l_run;
    asm volatile("s_waitcnt lgkmcnt(0)" ::: "memory");
    __builtin_amdgcn_s_barrier();
    __builtin_amdgcn_sched_barrier(0);
    #pragma unroll
    for (int ct = 0; ct < 4; ++ct) {
        int cg = 64 * w + 16 * ct + 4 * g;
        #pragma unroll
        for (int qg = 0; qg < 8; ++qg) {
            float inv = 1.0f / sLS[16 * qg + r16];
            long long row = (long long)b * S_ + s0 + 16 * qg + r16;
            ushort4 o;
            o.x = f2us(acc[ct][qg][0] * inv);
            o.y = f2us(acc[ct][qg][1] * inv);
            o.z = f2us(acc[ct][qg][2] * inv);
            o.w = f2us(acc[ct][qg][3] * inv);
            *reinterpret_cast<ushort4*>(outc + row * 8192 + h * 512 + cg) = o;
        }
    }
}

// ---------- workspace layout (bytes), total 221,773,824 ----------
extern "C" void kernel_launch(void* const* d_in, const int* in_sizes, int n_in,
                              void* d_out, int out_size, void* d_ws, size_t ws_size,
                              hipStream_t stream)
{
    if (ws_size < 221773824ULL) return;
    const float* x    = (const float*)d_in[0];
    const float* fc   = (const float*)d_in[1];
    const float* fs   = (const float*)d_in[2];
    const float* wq   = (const float*)d_in[3];
    const float* wkva = (const float*)d_in[4];
    const float* wkvb = (const float*)d_in[5];
    const float* wo   = (const float*)d_in[6];
    float* out = (float*)d_out;

    char* ws = (char*)d_ws;
    ushort_t* qcat  = (ushort_t*)(ws);
    ushort_t* outc  = (ushort_t*)(ws + 75497472);
    ushort_t* qb16  = (ushort_t*)(ws + 142606336);
    ushort_t* xb    = (ushort_t*)(ws + 167772160);
    ushort_t* aoutb = (ushort_t*)(ws + 167772160);   // alias xb (dead by step 8)
    ushort_t* wqb   = (ushort_t*)(ws + 184549376);
    ushort_t* kvb16 = (ushort_t*)(ws + 184549376);   // alias wqb (dead after gemm1)
    ushort_t* vT16  = (ushort_t*)(ws + 189267968);   // alias wqb tail
    float*    kvbuf = (float*)(ws + 197132288);
    ushort_t* wob   = (ushort_t*)(ws + 206569472);
    ushort_t* wkvab = (ushort_t*)(ws + 214958080);
    ushort_t* wnTb  = (ushort_t*)(ws + 217579520);
    ushort_t* wvb   = (ushort_t*)(ws + 219676672);

    // 0) all flat conversions in one launch + wnT transpose
    conv_all_k<<<dim3(20736), 256, 0, stream>>>(
        x, xb, wq, wqb, wo, wob, wkva, wkvab, wkvb, wvb);
    conv_wnt_k<<<dim3(4, 16, 16), 256, 0, stream>>>(wkvb, wnTb);
    // 1) q = x @ wq^T -> qb16
    gemm_mfma_k<ushort_t, false><<<dim3(24, 32, 1), 256, 0, stream>>>(
        xb, D_, 0, wqb, D_, 0, qb16, 3072, 0, D_, 3072);
    // 2) kv = x @ wkv_a^T -> kvbuf f32 (B padded to 640)
    gemm_mfma_k<float, true><<<dim3(5, 32, 1), 256, 0, stream>>>(
        xb, D_, 0, wkvab, D_, 0, kvbuf, CR_, 0, D_, CR_);
    // 3) rope q_pe -> qcat pe-part
    rope_q_k<<<dim3(BS_ * H_ * 32 / 256), 256, 0, stream>>>(qb16, qcat, fc, fs);
    // 4) rmsnorm c + rope k_pe -> kvb16
    kvpost_k<<<dim3(BS_), 256, 0, stream>>>(kvbuf, kvb16, fc, fs);
    // 5) transpose -> vT16
    vtrans_k<<<dim3(S_ / 32, C_ / 32, B_), 256, 0, stream>>>(kvb16, vT16);
    // 6) q_abs[h] = q_nope[h] @ wnT[h]^T -> qcat c-part (z=16)
    gemm_mfma_k<ushort_t, false><<<dim3(4, 32, 16), 256, 0, stream>>>(
        qb16, 3072, 192, wnTb, 128, 65536, qcat, 576, (long long)BS_ * 576, NOPE_, 512);
    // 7) MFMA attention (8-wave QB=128, c-split PV, shared P) -> outc
    attn_mfma_k<<<dim3(S_ / 128, B_ * H_), 512, 0, stream>>>(qcat, kvb16, vT16, outc);
    // 8) out_v[h] = out_c[h] @ w_v[h]^T -> aoutb bf16 (z=16)
    gemm_mfma_k<ushort_t, false><<<dim3(1, 32, 16), 256, 0, stream>>>(
        outc, 8192, 512, wvb, 512, 65536, aoutb, 2048, 128, C_, 128);
    // 9) final = aout @ wo^T -> f32 out
    gemm_mfma_k<float, false><<<dim3(16, 32, 1), 256, 0, stream>>>(
        aoutb, 2048, 0, wob, 2048, 0, out, D_, 0, 2048, 2048);
}

// Round 14
// 706.425 us; speedup vs baseline: 1.2418x; 1.2418x over previous
//
#include <hip/hip_runtime.h>

#define B_ 2
#define S_ 2048
#define D_ 2048
#define H_ 16
#define NOPE_ 128
#define ROPE_ 64
#define V_ 128
#define C_ 512
#define QK_ 192   // NOPE+ROPE
#define CR_ 576   // C+ROPE
#define BS_ 4096  // B*S

typedef unsigned short ushort_t;
typedef unsigned int uint_t;
typedef __attribute__((ext_vector_type(8))) short bf16x8;
typedef __attribute__((ext_vector_type(4))) float f32x4;

// async global->LDS, 16B per lane. LDS dest = wave-uniform base + lane*16.
#define GLD16(gp, lp) __builtin_amdgcn_global_load_lds( \
    (const __attribute__((address_space(1))) void*)(gp), \
    (__attribute__((address_space(3))) void*)(lp), 16, 0, 0)

__device__ __forceinline__ float us2f(ushort_t u) {
    unsigned int x = ((unsigned int)u) << 16;
    return __uint_as_float(x);
}
__device__ __forceinline__ ushort_t f2us(float f) {
    unsigned int x = __float_as_uint(f);
    unsigned int r = (x + 0x7fffu + ((x >> 16) & 1u)) >> 16;
    return (ushort_t)r;
}

// ---------- merged f32 -> bf16 conversions + wnT transpose (one launch) ----------
// block ranges: [0,8192) x | [8192,14336) wq | [14336,18432) wo
//               [18432,19712) wkva pad | [19712,20736) wv | [20736,21760) wnT
__global__ __launch_bounds__(256) void conv_all_k(
    const float* __restrict__ x,    ushort_t* __restrict__ xb,
    const float* __restrict__ wq,   ushort_t* __restrict__ wqb,
    const float* __restrict__ wo,   ushort_t* __restrict__ wob,
    const float* __restrict__ wkva, ushort_t* __restrict__ wkvab,
    const float* __restrict__ wkvb, ushort_t* __restrict__ wvb,
    ushort_t* __restrict__ wnT)
{
    __shared__ float st[32][33];
    int bid = blockIdx.x;
    if (bid < 8192) {
        long long i = ((long long)bid * 256 + threadIdx.x) * 4;
        float4 v = *reinterpret_cast<const float4*>(x + i);
        ushort4 o; o.x = f2us(v.x); o.y = f2us(v.y); o.z = f2us(v.z); o.w = f2us(v.w);
        *reinterpret_cast<ushort4*>(xb + i) = o;
    } else if (bid < 14336) {
        long long i = ((long long)(bid - 8192) * 256 + threadIdx.x) * 4;
        float4 v = *reinterpret_cast<const float4*>(wq + i);
        ushort4 o; o.x = f2us(v.x); o.y = f2us(v.y); o.z = f2us(v.z); o.w = f2us(v.w);
        *reinterpret_cast<ushort4*>(wqb + i) = o;
    } else if (bid < 18432) {
        long long i = ((long long)(bid - 14336) * 256 + threadIdx.x) * 4;
        float4 v = *reinterpret_cast<const float4*>(wo + i);
        ushort4 o; o.x = f2us(v.x); o.y = f2us(v.y); o.z = f2us(v.z); o.w = f2us(v.w);
        *reinterpret_cast<ushort4*>(wob + i) = o;
    } else if (bid < 19712) {
        long long i = ((long long)(bid - 18432) * 256 + threadIdx.x) * 4;
        int row = (int)(i >> 11);
        ushort4 o;
        if (row < 576) {
            float4 v = *reinterpret_cast<const float4*>(wkva + i);
            o.x = f2us(v.x); o.y = f2us(v.y); o.z = f2us(v.z); o.w = f2us(v.w);
        } else { o.x = o.y = o.z = o.w = 0; }
        *reinterpret_cast<ushort4*>(wkvab + i) = o;
    } else if (bid < 20736) {
        long long i = ((long long)(bid - 19712) * 256 + threadIdx.x) * 4;
        int h = (int)(i >> 16);
        int rem = (int)(i & 65535);
        float4 v = *reinterpret_cast<const float4*>(wkvb + (long long)h * 131072 + 65536 + rem);
        ushort4 o; o.x = f2us(v.x); o.y = f2us(v.y); o.z = f2us(v.z); o.w = f2us(v.w);
        *reinterpret_cast<ushort4*>(wvb + i) = o;
    } else {
        // wnT: w_nope (per h: rows 0..127 of 256x512) -> [h][512][128] transposed
        int bid2 = bid - 20736;                 // 0..1023, was grid dim3(4,16,16)
        int d0 = (bid2 & 3) * 32;
        int c0 = ((bid2 >> 2) & 15) * 32;
        int h  = bid2 >> 6;
        int t = threadIdx.x;
        int dl = t >> 3, c4 = (t & 7) * 4;
        float4 v = *reinterpret_cast<const float4*>(
            wkvb + (long long)h * 131072 + (d0 + dl) * 512 + c0 + c4);
        st[dl][c4] = v.x; st[dl][c4+1] = v.y; st[dl][c4+2] = v.z; st[dl][c4+3] = v.w;
        __syncthreads();
        int cl = t >> 3, d4 = (t & 7) * 4;
        ushort4 o;
        o.x = f2us(st[d4][cl]);   o.y = f2us(st[d4+1][cl]);
        o.z = f2us(st[d4+2][cl]); o.w = f2us(st[d4+3][cl]);
        *reinterpret_cast<ushort4*>(wnT + (long long)h * 65536 + (c0 + cl) * 128 + d0 + d4) = o;
    }
}

// ---------- MFMA GEMM (m97 structure) ----------
template <typename TC, bool NGUARD>
__global__ __launch_bounds__(256) void gemm_mfma_k(
    const ushort_t* __restrict__ A, int lda, long long strideAz,
    const ushort_t* __restrict__ Bm, int ldb, long long strideBz,
    TC* __restrict__ Cm, int ldc, long long strideCz,
    int K, int N_real)
{
    __shared__ ushort_t sA[128 * 32];
    __shared__ ushort_t sB[128 * 32];
    const int tid = threadIdx.x;
    const int w = tid >> 6, ln = tid & 63;
    const int g = ln >> 4, r16 = ln & 15;
    const int wr = w >> 1, wc = w & 1;
    const int z = blockIdx.z;
    A  += (long long)z * strideAz;
    Bm += (long long)z * strideBz;
    Cm += (long long)z * strideCz;
    const long long m0 = (long long)blockIdx.y * 128;
    const long long n0 = (long long)blockIdx.x * 128;

    const int r0 = tid >> 2, kc8 = (tid & 3) * 8;
    const ushort_t* a0 = A + (m0 + r0) * lda + kc8;
    const ushort_t* a1 = A + (m0 + 64 + r0) * lda + kc8;
    const ushort_t* b0 = Bm + (n0 + r0) * ldb + kc8;
    const ushort_t* b1 = Bm + (n0 + 64 + r0) * ldb + kc8;
    ushort_t* sA0 = sA + w * 512;
    ushort_t* sA1 = sA + 2048 + w * 512;
    ushort_t* sB0 = sB + w * 512;
    ushort_t* sB1 = sB + 2048 + w * 512;

    const f32x4 zero4 = {0.f, 0.f, 0.f, 0.f};
    f32x4 acc[4][4];
    #pragma unroll
    for (int i = 0; i < 4; ++i)
        #pragma unroll
        for (int j = 0; j < 4; ++j) acc[i][j] = zero4;

    for (int k0 = 0; k0 < K; k0 += 32) {
        GLD16(a0 + k0, sA0);
        GLD16(a1 + k0, sA1);
        GLD16(b0 + k0, sB0);
        GLD16(b1 + k0, sB1);
        __syncthreads();
        bf16x8 af[4], bfr[4];
        #pragma unroll
        for (int i = 0; i < 4; ++i)
            af[i] = *reinterpret_cast<const bf16x8*>(&sA[(64 * wr + 16 * i + r16) * 32 + 8 * g]);
        #pragma unroll
        for (int j = 0; j < 4; ++j)
            bfr[j] = *reinterpret_cast<const bf16x8*>(&sB[(64 * wc + 16 * j + r16) * 32 + 8 * g]);
        __builtin_amdgcn_s_setprio(1);
        #pragma unroll
        for (int i = 0; i < 4; ++i)
            #pragma unroll
            for (int j = 0; j < 4; ++j)
                acc[i][j] = __builtin_amdgcn_mfma_f32_16x16x32_bf16(af[i], bfr[j], acc[i][j], 0, 0, 0);
        __builtin_amdgcn_s_setprio(0);
        __syncthreads();
    }
    #pragma unroll
    for (int i = 0; i < 4; ++i) {
        #pragma unroll
        for (int j = 0; j < 4; ++j) {
            int nn = (int)n0 + 64 * wc + 16 * j + r16;
            if (NGUARD && nn >= N_real) continue;
            #pragma unroll
            for (int r = 0; r < 4; ++r) {
                long long row = m0 + 64 * wr + 16 * i + 4 * g + r;
                float v = acc[i][j][r];
                if constexpr (sizeof(TC) == 2) Cm[row * ldc + nn] = (TC)f2us(v);
                else                           Cm[row * ldc + nn] = (TC)v;
            }
        }
    }
}

// ---------- RoPE on q_pe ----------
__global__ __launch_bounds__(256) void rope_q_k(
    const ushort_t* __restrict__ qb, ushort_t* __restrict__ qcat,
    const float* __restrict__ fc, const float* __restrict__ fs)
{
    int id = blockIdx.x * 256 + threadIdx.x;
    int i  = id & 31;
    int h  = (id >> 5) & 15;
    int bs = id >> 9;
    int s  = bs & (S_ - 1);
    float c  = fc[s * 32 + i];
    float sn = fs[s * 32 + i];
    uint_t w2 = *reinterpret_cast<const uint_t*>(
        qb + (long long)bs * 3072 + h * QK_ + NOPE_ + 2 * i);
    float tr = us2f((ushort_t)(w2 & 0xffffu));
    float ti = us2f((ushort_t)(w2 >> 16));
    float orr = tr * c - ti * sn;
    float oii = tr * sn + ti * c;
    uint_t wrd = (uint_t)f2us(orr) | ((uint_t)f2us(oii) << 16);
    ((uint_t*)qcat)[((long long)h * BS_ + bs) * 288 + 256 + i] = wrd;
}

// ---------- kv post ----------
__global__ __launch_bounds__(256) void kvpost_k(
    const float* __restrict__ kv, ushort_t* __restrict__ kvb16,
    const float* __restrict__ fc, const float* __restrict__ fs)
{
    int bs = blockIdx.x;
    const float* row = kv + (long long)bs * CR_;
    ushort_t* orow = kvb16 + (long long)bs * CR_;
    int tid = threadIdx.x;
    float v0 = row[tid], v1 = row[tid + 256];
    float ss = v0 * v0 + v1 * v1;
    #pragma unroll
    for (int m = 1; m < 64; m <<= 1) ss += __shfl_xor(ss, m, 64);
    __shared__ float red[4];
    if ((tid & 63) == 0) red[tid >> 6] = ss;
    __syncthreads();
    float tot = red[0] + red[1] + red[2] + red[3];
    float r = rsqrtf(tot * (1.0f / (float)C_) + 1e-6f);
    orow[tid] = f2us(v0 * r);
    orow[tid + 256] = f2us(v1 * r);
    if (tid < 32) {
        int s = bs & (S_ - 1);
        float c  = fc[s * 32 + tid];
        float sn = fs[s * 32 + tid];
        float tr = row[C_ + 2 * tid], ti = row[C_ + 2 * tid + 1];
        orow[C_ + 2 * tid]     = f2us(tr * c - ti * sn);
        orow[C_ + 2 * tid + 1] = f2us(tr * sn + ti * c);
    }
}

// ---------- transpose c-part of kvb16 -> vT16 [B][512][2048] ----------
__global__ __launch_bounds__(256) void vtrans_k(
    const ushort_t* __restrict__ kvb16, ushort_t* __restrict__ vT16)
{
    __shared__ ushort_t st[32][36];
    int b = blockIdx.z;
    int s0 = blockIdx.x * 32, c0 = blockIdx.y * 32;
    int t = threadIdx.x;
    int sl = t >> 3, c4 = (t & 7) * 4;
    ushort4 v = *reinterpret_cast<const ushort4*>(
        kvb16 + ((long long)(b * S_ + s0 + sl)) * CR_ + c0 + c4);
    st[sl][c4] = v.x; st[sl][c4+1] = v.y; st[sl][c4+2] = v.z; st[sl][c4+3] = v.w;
    __syncthreads();
    int cl = t >> 3, s4 = (t & 7) * 4;
    ushort4 o;
    o.x = st[s4][cl]; o.y = st[s4+1][cl]; o.z = st[s4+2][cl]; o.w = st[s4+3][cl];
    *reinterpret_cast<ushort4*>(
        vT16 + ((long long)b * 512 + c0 + cl) * 2048 + s0 + s4) = o;
}

// ---------- MFMA flash attention: 8 waves, QB=128, wave-local P, 1 barrier/iter (R7) ----------
__global__ __launch_bounds__(512, 2) void attn_mfma_k(
    const ushort_t* __restrict__ qcat,   // [H][BS][576] bf16
    const ushort_t* __restrict__ kvb16,  // [BS][576] bf16
    const ushort_t* __restrict__ vT16,   // [B][512][2048] bf16
    ushort_t* __restrict__ outc)         // [BS][H*512] bf16
{
    __shared__ ushort_t sKV[2 * 32 * 576];   // XOR-swizzled 16B chunks (low3 ^ row)
    __shared__ ushort_t sVT[2 * 512 * 32];   // line-pair chunk-XOR swizzle

    const int tid = threadIdx.x;
    const int w   = tid >> 6;          // 0..7
    const int ln  = tid & 63;
    const int g   = ln >> 4;
    const int r16 = ln & 15;
    const int bh = blockIdx.y;
    const int b = bh >> 4, h = bh & 15;
    const int s0 = blockIdx.x * 128;

    // staging source offsets (inverse-swizzled), 512-thread partition
    int kvoff[4], kvoff4 = 0;
    #pragma unroll
    for (int i = 0; i < 4; ++i) {
        int p = i * 512 + tid;          // 16B-chunk 0..2047
        int row = p / 72, cs = p - row * 72;
        kvoff[i] = row * 576 + ((cs & ~7) | ((cs ^ row) & 7)) * 8;
    }
    if (w < 4) {
        int p = 2048 + tid;             // chunk 2048..2303
        int row = p / 72, cs = p - row * 72;
        kvoff4 = row * 576 + ((cs & ~7) | ((cs ^ row) & 7)) * 8;
    }
    int vtoff[4];
    #pragma unroll
    for (int i = 0; i < 4; ++i) {
        int p = i * 512 + tid;          // chunk 0..2047
        int rp = p >> 3, sw = p & 7;
        int lg = sw ^ (rp & 7);
        vtoff[i] = (2 * rp + (lg >> 2)) * 2048 + (lg & 3) * 8;
    }

    // Q fragments (B-operand: col=l&15=q-row, k=8g+j); wave w owns q rows s0+16w..+15
    bf16x8 qfrag[18];
    {
        const ushort_t* qp = qcat
            + ((long long)h * BS_ + (long long)b * S_ + (s0 + 16 * w + r16)) * 576 + 8 * g;
        #pragma unroll
        for (int kt = 0; kt < 18; ++kt)
            qfrag[kt] = *reinterpret_cast<const bf16x8*>(qp + 32 * kt);
    }

    const f32x4 zero4 = {0.f, 0.f, 0.f, 0.f};
    f32x4 acc[32];                      // out^T[c=16ct+4g+reg][q=own r16]
    #pragma unroll
    for (int i = 0; i < 32; ++i) acc[i] = zero4;

    float m_run = -1e30f, l_run = 0.0f;
    const float scale = 0.0721687836487032f;  // 192^-0.5

    const ushort_t* kvsrc = kvb16 + (long long)b * S_ * 576;
    const ushort_t* vtsrc = vT16 + (long long)b * 512 * 2048;
    char* skvb = (char*)sKV;
    char* svtb = (char*)sVT;

#define STAGE_TILE(T0, DB) do { \
        const ushort_t* kvt_ = kvsrc + (long long)(T0) * 576; \
        const ushort_t* vtt_ = vtsrc + (T0); \
        _Pragma("unroll") \
        for (int i_ = 0; i_ < 4; ++i_) \
            GLD16(kvt_ + kvoff[i_], skvb + (DB) * 36864 + i_ * 8192 + w * 1024); \
        if (w < 4) GLD16(kvt_ + kvoff4, skvb + (DB) * 36864 + 32768 + w * 1024); \
        _Pragma("unroll") \
        for (int i_ = 0; i_ < 4; ++i_) \
            GLD16(vtt_ + vtoff[i_], svtb + (DB) * 32768 + i_ * 8192 + w * 1024); \
    } while (0)

    STAGE_TILE(0, 0);   // prologue

    for (int t = 0; t < 64; ++t) {
        const int cur = t & 1;
        asm volatile("s_waitcnt vmcnt(0)" ::: "memory");   // own share of tile t landed
        __builtin_amdgcn_s_barrier();                       // all shares landed; bufs free
        __builtin_amdgcn_sched_barrier(0);
        if (t < 63) STAGE_TILE((t + 1) * 32, cur ^ 1);

        // scores^T = mfma(A=KV rows, B=Q): 4 chains of 9
        const int kvb = cur * 18432;
        f32x4 d0a = zero4, d0b = zero4, d1a = zero4, d1b = zero4;
        __builtin_amdgcn_s_setprio(1);
        #pragma unroll
        for (int kt = 0; kt < 9; ++kt) {
            int ch = kt * 4 + g;
            int chs = (ch & ~7) | ((ch ^ r16) & 7);
            bf16x8 a0 = *reinterpret_cast<const bf16x8*>(&sKV[kvb + r16 * 576 + chs * 8]);
            bf16x8 a1 = *reinterpret_cast<const bf16x8*>(&sKV[kvb + (16 + r16) * 576 + chs * 8]);
            d0a = __builtin_amdgcn_mfma_f32_16x16x32_bf16(a0, qfrag[kt], d0a, 0, 0, 0);
            d1a = __builtin_amdgcn_mfma_f32_16x16x32_bf16(a1, qfrag[kt], d1a, 0, 0, 0);
        }
        #pragma unroll
        for (int kt = 9; kt < 18; ++kt) {
            int ch = kt * 4 + g;
            int chs = (ch & ~7) | ((ch ^ r16) & 7);
            bf16x8 a0 = *reinterpret_cast<const bf16x8*>(&sKV[kvb + r16 * 576 + chs * 8]);
            bf16x8 a1 = *reinterpret_cast<const bf16x8*>(&sKV[kvb + (16 + r16) * 576 + chs * 8]);
            d0b = __builtin_amdgcn_mfma_f32_16x16x32_bf16(a0, qfrag[kt], d0b, 0, 0, 0);
            d1b = __builtin_amdgcn_mfma_f32_16x16x32_bf16(a1, qfrag[kt], d1b, 0, 0, 0);
        }
        __builtin_amdgcn_s_setprio(0);
        f32x4 d0 = d0a + d0b, d1 = d1a + d1b;

        // lane-local online softmax (lane owns q-row 16w+r16; t spread over 4 g-groups)
        float p[8];
        #pragma unroll
        for (int i = 0; i < 4; ++i) { p[i] = d0[i] * scale; p[4 + i] = d1[i] * scale; }
        float mt = p[0];
        #pragma unroll
        for (int i = 1; i < 8; ++i) mt = fmaxf(mt, p[i]);
        mt = fmaxf(mt, __shfl_xor(mt, 16, 64));
        mt = fmaxf(mt, __shfl_xor(mt, 32, 64));
        bool anyneed = __any(mt > m_run + 8.0f);   // defer-max THR=8 (wave-local)
        float m_new = anyneed ? fmaxf(m_run, mt) : m_run;
        float fac = anyneed ? __expf(m_run - m_new) : 1.0f;
        m_run = m_new;
        float lt = 0.f;
        #pragma unroll
        for (int i = 0; i < 8; ++i) { p[i] = __expf(p[i] - m_new); lt += p[i]; }
        lt += __shfl_xor(lt, 16, 64);
        lt += __shfl_xor(lt, 32, 64);
        l_run = l_run * fac + lt;

        // P -> bf16 words: w0=(t:4g,4g+1) w1=(4g+2,4g+3) w2=(16+4g,16+4g+1) w3=(16+4g+2,+3)
        uint_t w0, w1, w2, w3;
        asm("v_cvt_pk_bf16_f32 %0, %1, %2" : "=v"(w0) : "v"(p[0]), "v"(p[1]));
        asm("v_cvt_pk_bf16_f32 %0, %1, %2" : "=v"(w1) : "v"(p[2]), "v"(p[3]));
        asm("v_cvt_pk_bf16_f32 %0, %1, %2" : "=v"(w2) : "v"(p[4]), "v"(p[5]));
        asm("v_cvt_pk_bf16_f32 %0, %1, %2" : "=v"(w3) : "v"(p[6]), "v"(p[7]));
        // redistribute: lane group g' needs t = 8g'..8g'+7 for its own q-col r16
        uint_t xa = (uint_t)__shfl_xor((int)((g & 1) ? w0 : w2), 16, 64);
        uint_t xb = (uint_t)__shfl_xor((int)((g & 1) ? w1 : w3), 16, 64);
        uint_t ya = (uint_t)__shfl_xor((int)((g >> 1) ? w0 : w2), 32, 64);
        uint_t yb = (uint_t)__shfl_xor((int)((g >> 1) ? w1 : w3), 32, 64);
        uint_t za = (uint_t)__shfl_xor((int)((g == 1) ? w2 : w0), 48, 64);
        uint_t zb = (uint_t)__shfl_xor((int)((g == 1) ? w3 : w1), 48, 64);
        uint_t pw[4];
        if      (g == 0) { pw[0] = w0; pw[1] = w1; pw[2] = xa; pw[3] = xb; }
        else if (g == 1) { pw[0] = za; pw[1] = zb; pw[2] = ya; pw[3] = yb; }
        else if (g == 2) { pw[0] = ya; pw[1] = yb; pw[2] = za; pw[3] = zb; }
        else             { pw[0] = xa; pw[1] = xb; pw[2] = w2; pw[3] = w3; }
        bf16x8 pB = *reinterpret_cast<bf16x8*>(pw);

        // rescale own acc (fac is lane-local: col q = r16)
        if (anyneed) {
            #pragma unroll
            for (int ct = 0; ct < 32; ++ct) {
                acc[ct][0] *= fac; acc[ct][1] *= fac;
                acc[ct][2] *= fac; acc[ct][3] *= fac;
            }
        }
        // PV: out^T = mfma(A=V^T rows, B=own P); all 512 c rows, own 16 q cols
        const int vtb = cur * 16384;
        __builtin_amdgcn_s_setprio(1);
        #pragma unroll
        for (int ct = 0; ct < 32; ++ct) {
            int c = 16 * ct + r16;
            int sw = ((c & 1) * 4 + g) ^ ((c >> 1) & 7);
            bf16x8 aV = *reinterpret_cast<const bf16x8*>(&sVT[vtb + (c >> 1) * 64 + sw * 8]);
            acc[ct] = __builtin_amdgcn_mfma_f32_16x16x32_bf16(aV, pB, acc[ct], 0, 0, 0);
        }
        __builtin_amdgcn_s_setprio(0);
    }
#undef STAGE_TILE

    // finalize: everything lane-local
    float inv = 1.0f / l_run;
    long long row = (long long)b * S_ + s0 + 16 * w + r16;
    ushort_t* obase = outc + row * 8192 + h * 512;
    #pragma unroll
    for (int ct = 0; ct < 32; ++ct) {
        int cg = 16 * ct + 4 * g;
        ushort4 o;
        o.x = f2us(acc[ct][0] * inv);
        o.y = f2us(acc[ct][1] * inv);
        o.z = f2us(acc[ct][2] * inv);
        o.w = f2us(acc[ct][3] * inv);
        *reinterpret_cast<ushort4*>(obase + cg) = o;
    }
}

// ---------- workspace layout (bytes), total 221,773,824 ----------
extern "C" void kernel_launch(void* const* d_in, const int* in_sizes, int n_in,
                              void* d_out, int out_size, void* d_ws, size_t ws_size,
                              hipStream_t stream)
{
    if (ws_size < 221773824ULL) return;
    const float* x    = (const float*)d_in[0];
    const float* fc   = (const float*)d_in[1];
    const float* fs   = (const float*)d_in[2];
    const float* wq   = (const float*)d_in[3];
    const float* wkva = (const float*)d_in[4];
    const float* wkvb = (const float*)d_in[5];
    const float* wo   = (const float*)d_in[6];
    float* out = (float*)d_out;

    char* ws = (char*)d_ws;
    ushort_t* qcat  = (ushort_t*)(ws);
    ushort_t* outc  = (ushort_t*)(ws + 75497472);
    ushort_t* qb16  = (ushort_t*)(ws + 142606336);
    ushort_t* xb    = (ushort_t*)(ws + 167772160);
    ushort_t* aoutb = (ushort_t*)(ws + 167772160);   // alias xb (dead by step 8)
    ushort_t* wqb   = (ushort_t*)(ws + 184549376);
    ushort_t* kvb16 = (ushort_t*)(ws + 184549376);   // alias wqb (dead after gemm1)
    ushort_t* vT16  = (ushort_t*)(ws + 189267968);   // alias wqb tail
    float*    kvbuf = (float*)(ws + 197132288);
    ushort_t* wob   = (ushort_t*)(ws + 206569472);
    ushort_t* wkvab = (ushort_t*)(ws + 214958080);
    ushort_t* wnTb  = (ushort_t*)(ws + 217579520);
    ushort_t* wvb   = (ushort_t*)(ws + 219676672);

    // 0) all conversions + wnT transpose in one launch
    conv_all_k<<<dim3(21760), 256, 0, stream>>>(
        x, xb, wq, wqb, wo, wob, wkva, wkvab, wkvb, wvb, wnTb);
    // 1) q = x @ wq^T -> qb16
    gemm_mfma_k<ushort_t, false><<<dim3(24, 32, 1), 256, 0, stream>>>(
        xb, D_, 0, wqb, D_, 0, qb16, 3072, 0, D_, 3072);
    // 2) kv = x @ wkv_a^T -> kvbuf f32 (B padded to 640)
    gemm_mfma_k<float, true><<<dim3(5, 32, 1), 256, 0, stream>>>(
        xb, D_, 0, wkvab, D_, 0, kvbuf, CR_, 0, D_, CR_);
    // 3) rope q_pe -> qcat pe-part
    rope_q_k<<<dim3(BS_ * H_ * 32 / 256), 256, 0, stream>>>(qb16, qcat, fc, fs);
    // 4) rmsnorm c + rope k_pe -> kvb16
    kvpost_k<<<dim3(BS_), 256, 0, stream>>>(kvbuf, kvb16, fc, fs);
    // 5) transpose -> vT16
    vtrans_k<<<dim3(S_ / 32, C_ / 32, B_), 256, 0, stream>>>(kvb16, vT16);
    // 6) q_abs[h] = q_nope[h] @ wnT[h]^T -> qcat c-part (z=16)
    gemm_mfma_k<ushort_t, false><<<dim3(4, 32, 16), 256, 0, stream>>>(
        qb16, 3072, 192, wnTb, 128, 65536, qcat, 576, (long long)BS_ * 576, NOPE_, 512);
    // 7) MFMA attention (8-wave QB=128, wave-local P, 1 barrier/iter) -> outc
    attn_mfma_k<<<dim3(S_ / 128, B_ * H_), 512, 0, stream>>>(qcat, kvb16, vT16, outc);
    // 8) out_v[h] = out_c[h] @ w_v[h]^T -> aoutb bf16 (z=16)
    gemm_mfma_k<ushort_t, false><<<dim3(1, 32, 16), 256, 0, stream>>>(
        outc, 8192, 512, wvb, 512, 65536, aoutb, 2048, 128, C_, 128);
    // 9) final = aout @ wo^T -> f32 out
    gemm_mfma_k<float, false><<<dim3(16, 32, 1), 256, 0, stream>>>(
        aoutb, 2048, 0, wob, 2048, 0, out, D_, 0, 2048, 2048);
}

// Round 15
// 689.924 us; speedup vs baseline: 1.2715x; 1.0239x over previous
//
#include <hip/hip_runtime.h>

#define B_ 2
#define S_ 2048
#define D_ 2048
#define H_ 16
#define NOPE_ 128
#define ROPE_ 64
#define V_ 128
#define C_ 512
#define QK_ 192   // NOPE+ROPE
#define CR_ 576   // C+ROPE
#define BS_ 4096  // B*S

typedef unsigned short ushort_t;
typedef unsigned int uint_t;
typedef __attribute__((ext_vector_type(8))) short bf16x8;
typedef __attribute__((ext_vector_type(4))) float f32x4;

// async global->LDS, 16B per lane. LDS dest = wave-uniform base + lane*16.
#define GLD16(gp, lp) __builtin_amdgcn_global_load_lds( \
    (const __attribute__((address_space(1))) void*)(gp), \
    (__attribute__((address_space(3))) void*)(lp), 16, 0, 0)

__device__ __forceinline__ float us2f(ushort_t u) {
    unsigned int x = ((unsigned int)u) << 16;
    return __uint_as_float(x);
}
__device__ __forceinline__ ushort_t f2us(float f) {
    unsigned int x = __float_as_uint(f);
    unsigned int r = (x + 0x7fffu + ((x >> 16) & 1u)) >> 16;
    return (ushort_t)r;
}

// ---------- merged f32 -> bf16 conversions + wnT transpose (one launch) ----------
// block ranges: [0,8192) x | [8192,14336) wq | [14336,18432) wo
//               [18432,19712) wkva pad | [19712,20736) wv | [20736,21760) wnT
__global__ __launch_bounds__(256) void conv_all_k(
    const float* __restrict__ x,    ushort_t* __restrict__ xb,
    const float* __restrict__ wq,   ushort_t* __restrict__ wqb,
    const float* __restrict__ wo,   ushort_t* __restrict__ wob,
    const float* __restrict__ wkva, ushort_t* __restrict__ wkvab,
    const float* __restrict__ wkvb, ushort_t* __restrict__ wvb,
    ushort_t* __restrict__ wnT)
{
    __shared__ float st[32][33];
    int bid = blockIdx.x;
    if (bid < 8192) {
        long long i = ((long long)bid * 256 + threadIdx.x) * 4;
        float4 v = *reinterpret_cast<const float4*>(x + i);
        ushort4 o; o.x = f2us(v.x); o.y = f2us(v.y); o.z = f2us(v.z); o.w = f2us(v.w);
        *reinterpret_cast<ushort4*>(xb + i) = o;
    } else if (bid < 14336) {
        long long i = ((long long)(bid - 8192) * 256 + threadIdx.x) * 4;
        float4 v = *reinterpret_cast<const float4*>(wq + i);
        ushort4 o; o.x = f2us(v.x); o.y = f2us(v.y); o.z = f2us(v.z); o.w = f2us(v.w);
        *reinterpret_cast<ushort4*>(wqb + i) = o;
    } else if (bid < 18432) {
        long long i = ((long long)(bid - 14336) * 256 + threadIdx.x) * 4;
        float4 v = *reinterpret_cast<const float4*>(wo + i);
        ushort4 o; o.x = f2us(v.x); o.y = f2us(v.y); o.z = f2us(v.z); o.w = f2us(v.w);
        *reinterpret_cast<ushort4*>(wob + i) = o;
    } else if (bid < 19712) {
        long long i = ((long long)(bid - 18432) * 256 + threadIdx.x) * 4;
        int row = (int)(i >> 11);
        ushort4 o;
        if (row < 576) {
            float4 v = *reinterpret_cast<const float4*>(wkva + i);
            o.x = f2us(v.x); o.y = f2us(v.y); o.z = f2us(v.z); o.w = f2us(v.w);
        } else { o.x = o.y = o.z = o.w = 0; }
        *reinterpret_cast<ushort4*>(wkvab + i) = o;
    } else if (bid < 20736) {
        long long i = ((long long)(bid - 19712) * 256 + threadIdx.x) * 4;
        int h = (int)(i >> 16);
        int rem = (int)(i & 65535);
        float4 v = *reinterpret_cast<const float4*>(wkvb + (long long)h * 131072 + 65536 + rem);
        ushort4 o; o.x = f2us(v.x); o.y = f2us(v.y); o.z = f2us(v.z); o.w = f2us(v.w);
        *reinterpret_cast<ushort4*>(wvb + i) = o;
    } else {
        // wnT: w_nope (per h: rows 0..127 of 256x512) -> [h][512][128] transposed
        int bid2 = bid - 20736;                 // 0..1023, was grid dim3(4,16,16)
        int d0 = (bid2 & 3) * 32;
        int c0 = ((bid2 >> 2) & 15) * 32;
        int h  = bid2 >> 6;
        int t = threadIdx.x;
        int dl = t >> 3, c4 = (t & 7) * 4;
        float4 v = *reinterpret_cast<const float4*>(
            wkvb + (long long)h * 131072 + (d0 + dl) * 512 + c0 + c4);
        st[dl][c4] = v.x; st[dl][c4+1] = v.y; st[dl][c4+2] = v.z; st[dl][c4+3] = v.w;
        __syncthreads();
        int cl = t >> 3, d4 = (t & 7) * 4;
        ushort4 o;
        o.x = f2us(st[d4][cl]);   o.y = f2us(st[d4+1][cl]);
        o.z = f2us(st[d4+2][cl]); o.w = f2us(st[d4+3][cl]);
        *reinterpret_cast<ushort4*>(wnT + (long long)h * 65536 + (c0 + cl) * 128 + d0 + d4) = o;
    }
}

// ---------- fused q-proj + kv-proj GEMM (steps 1+2 in one launch) ----------
// grid (29, 32): bx<24 -> q = x@wq^T -> qb16 bf16 [BS][3072], n0=bx*128
//                bx>=24 -> kv = x@wkva^T -> kvbuf f32 [BS][576] (B padded 640), guard nn<576
__global__ __launch_bounds__(256) void gemm12_k(
    const ushort_t* __restrict__ A,      // xb [BS][2048]
    const ushort_t* __restrict__ Bq,     // wqb [3072][2048]
    const ushort_t* __restrict__ Bkv,    // wkvab [640][2048]
    ushort_t* __restrict__ Cq,           // qb16
    float* __restrict__ Ckv)             // kvbuf
{
    __shared__ ushort_t sA[128 * 32];
    __shared__ ushort_t sB[128 * 32];
    const int tid = threadIdx.x;
    const int w = tid >> 6, ln = tid & 63;
    const int g = ln >> 4, r16 = ln & 15;
    const int wr = w >> 1, wc = w & 1;
    const bool isq = (blockIdx.x < 24);
    const ushort_t* Bm = isq ? Bq : Bkv;
    const long long m0 = (long long)blockIdx.y * 128;
    const long long n0 = (long long)(isq ? blockIdx.x : (blockIdx.x - 24)) * 128;

    const int r0 = tid >> 2, kc8 = (tid & 3) * 8;
    const ushort_t* a0 = A + (m0 + r0) * 2048 + kc8;
    const ushort_t* a1 = A + (m0 + 64 + r0) * 2048 + kc8;
    const ushort_t* b0 = Bm + (n0 + r0) * 2048 + kc8;
    const ushort_t* b1 = Bm + (n0 + 64 + r0) * 2048 + kc8;
    ushort_t* sA0 = sA + w * 512;
    ushort_t* sA1 = sA + 2048 + w * 512;
    ushort_t* sB0 = sB + w * 512;
    ushort_t* sB1 = sB + 2048 + w * 512;

    const f32x4 zero4 = {0.f, 0.f, 0.f, 0.f};
    f32x4 acc[4][4];
    #pragma unroll
    for (int i = 0; i < 4; ++i)
        #pragma unroll
        for (int j = 0; j < 4; ++j) acc[i][j] = zero4;

    for (int k0 = 0; k0 < 2048; k0 += 32) {
        GLD16(a0 + k0, sA0);
        GLD16(a1 + k0, sA1);
        GLD16(b0 + k0, sB0);
        GLD16(b1 + k0, sB1);
        __syncthreads();
        bf16x8 af[4], bfr[4];
        #pragma unroll
        for (int i = 0; i < 4; ++i)
            af[i] = *reinterpret_cast<const bf16x8*>(&sA[(64 * wr + 16 * i + r16) * 32 + 8 * g]);
        #pragma unroll
        for (int j = 0; j < 4; ++j)
            bfr[j] = *reinterpret_cast<const bf16x8*>(&sB[(64 * wc + 16 * j + r16) * 32 + 8 * g]);
        __builtin_amdgcn_s_setprio(1);
        #pragma unroll
        for (int i = 0; i < 4; ++i)
            #pragma unroll
            for (int j = 0; j < 4; ++j)
                acc[i][j] = __builtin_amdgcn_mfma_f32_16x16x32_bf16(af[i], bfr[j], acc[i][j], 0, 0, 0);
        __builtin_amdgcn_s_setprio(0);
        __syncthreads();
    }
    #pragma unroll
    for (int i = 0; i < 4; ++i) {
        #pragma unroll
        for (int j = 0; j < 4; ++j) {
            int nn = (int)n0 + 64 * wc + 16 * j + r16;
            #pragma unroll
            for (int r = 0; r < 4; ++r) {
                long long row = m0 + 64 * wr + 16 * i + 4 * g + r;
                float v = acc[i][j][r];
                if (isq)            Cq[row * 3072 + nn] = f2us(v);
                else if (nn < CR_)  Ckv[row * 576 + nn] = v;
            }
        }
    }
}

// ---------- MFMA GEMM (m97 structure; steps 6,8,9) ----------
template <typename TC, bool NGUARD>
__global__ __launch_bounds__(256) void gemm_mfma_k(
    const ushort_t* __restrict__ A, int lda, long long strideAz,
    const ushort_t* __restrict__ Bm, int ldb, long long strideBz,
    TC* __restrict__ Cm, int ldc, long long strideCz,
    int K, int N_real)
{
    __shared__ ushort_t sA[128 * 32];
    __shared__ ushort_t sB[128 * 32];
    const int tid = threadIdx.x;
    const int w = tid >> 6, ln = tid & 63;
    const int g = ln >> 4, r16 = ln & 15;
    const int wr = w >> 1, wc = w & 1;
    const int z = blockIdx.z;
    A  += (long long)z * strideAz;
    Bm += (long long)z * strideBz;
    Cm += (long long)z * strideCz;
    const long long m0 = (long long)blockIdx.y * 128;
    const long long n0 = (long long)blockIdx.x * 128;

    const int r0 = tid >> 2, kc8 = (tid & 3) * 8;
    const ushort_t* a0 = A + (m0 + r0) * lda + kc8;
    const ushort_t* a1 = A + (m0 + 64 + r0) * lda + kc8;
    const ushort_t* b0 = Bm + (n0 + r0) * ldb + kc8;
    const ushort_t* b1 = Bm + (n0 + 64 + r0) * ldb + kc8;
    ushort_t* sA0 = sA + w * 512;
    ushort_t* sA1 = sA + 2048 + w * 512;
    ushort_t* sB0 = sB + w * 512;
    ushort_t* sB1 = sB + 2048 + w * 512;

    const f32x4 zero4 = {0.f, 0.f, 0.f, 0.f};
    f32x4 acc[4][4];
    #pragma unroll
    for (int i = 0; i < 4; ++i)
        #pragma unroll
        for (int j = 0; j < 4; ++j) acc[i][j] = zero4;

    for (int k0 = 0; k0 < K; k0 += 32) {
        GLD16(a0 + k0, sA0);
        GLD16(a1 + k0, sA1);
        GLD16(b0 + k0, sB0);
        GLD16(b1 + k0, sB1);
        __syncthreads();
        bf16x8 af[4], bfr[4];
        #pragma unroll
        for (int i = 0; i < 4; ++i)
            af[i] = *reinterpret_cast<const bf16x8*>(&sA[(64 * wr + 16 * i + r16) * 32 + 8 * g]);
        #pragma unroll
        for (int j = 0; j < 4; ++j)
            bfr[j] = *reinterpret_cast<const bf16x8*>(&sB[(64 * wc + 16 * j + r16) * 32 + 8 * g]);
        __builtin_amdgcn_s_setprio(1);
        #pragma unroll
        for (int i = 0; i < 4; ++i)
            #pragma unroll
            for (int j = 0; j < 4; ++j)
                acc[i][j] = __builtin_amdgcn_mfma_f32_16x16x32_bf16(af[i], bfr[j], acc[i][j], 0, 0, 0);
        __builtin_amdgcn_s_setprio(0);
        __syncthreads();
    }
    #pragma unroll
    for (int i = 0; i < 4; ++i) {
        #pragma unroll
        for (int j = 0; j < 4; ++j) {
            int nn = (int)n0 + 64 * wc + 16 * j + r16;
            if (NGUARD && nn >= N_real) continue;
            #pragma unroll
            for (int r = 0; r < 4; ++r) {
                long long row = m0 + 64 * wr + 16 * i + 4 * g + r;
                float v = acc[i][j][r];
                if constexpr (sizeof(TC) == 2) Cm[row * ldc + nn] = (TC)f2us(v);
                else                           Cm[row * ldc + nn] = (TC)v;
            }
        }
    }
}

// ---------- merged RoPE(q_pe) + kvpost (steps 3+4 in one launch) ----------
// bid < 8192: rope on q_pe -> qcat pe-part.  bid >= 8192: rmsnorm+rope -> kvb16 (bs = bid-8192)
__global__ __launch_bounds__(256) void ropekv_k(
    const ushort_t* __restrict__ qb, ushort_t* __restrict__ qcat,
    const float* __restrict__ kv, ushort_t* __restrict__ kvb16,
    const float* __restrict__ fc, const float* __restrict__ fs)
{
    __shared__ float red[4];
    int bid = blockIdx.x;
    int tid = threadIdx.x;
    if (bid < 8192) {
        int id = bid * 256 + tid;           // BS*H*32 total
        int i  = id & 31;
        int h  = (id >> 5) & 15;
        int bs = id >> 9;
        int s  = bs & (S_ - 1);
        float c  = fc[s * 32 + i];
        float sn = fs[s * 32 + i];
        uint_t w2 = *reinterpret_cast<const uint_t*>(
            qb + (long long)bs * 3072 + h * QK_ + NOPE_ + 2 * i);
        float tr = us2f((ushort_t)(w2 & 0xffffu));
        float ti = us2f((ushort_t)(w2 >> 16));
        float orr = tr * c - ti * sn;
        float oii = tr * sn + ti * c;
        uint_t wrd = (uint_t)f2us(orr) | ((uint_t)f2us(oii) << 16);
        ((uint_t*)qcat)[((long long)h * BS_ + bs) * 288 + 256 + i] = wrd;
    } else {
        int bs = bid - 8192;
        const float* row = kv + (long long)bs * CR_;
        ushort_t* orow = kvb16 + (long long)bs * CR_;
        float v0 = row[tid], v1 = row[tid + 256];
        float ss = v0 * v0 + v1 * v1;
        #pragma unroll
        for (int m = 1; m < 64; m <<= 1) ss += __shfl_xor(ss, m, 64);
        if ((tid & 63) == 0) red[tid >> 6] = ss;
        __syncthreads();
        float tot = red[0] + red[1] + red[2] + red[3];
        float r = rsqrtf(tot * (1.0f / (float)C_) + 1e-6f);
        orow[tid] = f2us(v0 * r);
        orow[tid + 256] = f2us(v1 * r);
        if (tid < 32) {
            int s = bs & (S_ - 1);
            float c  = fc[s * 32 + tid];
            float sn = fs[s * 32 + tid];
            float tr = row[C_ + 2 * tid], ti = row[C_ + 2 * tid + 1];
            orow[C_ + 2 * tid]     = f2us(tr * c - ti * sn);
            orow[C_ + 2 * tid + 1] = f2us(tr * sn + ti * c);
        }
    }
}

// ---------- transpose c-part of kvb16 -> vT16 [B][512][2048] ----------
__global__ __launch_bounds__(256) void vtrans_k(
    const ushort_t* __restrict__ kvb16, ushort_t* __restrict__ vT16)
{
    __shared__ ushort_t st[32][36];
    int b = blockIdx.z;
    int s0 = blockIdx.x * 32, c0 = blockIdx.y * 32;
    int t = threadIdx.x;
    int sl = t >> 3, c4 = (t & 7) * 4;
    ushort4 v = *reinterpret_cast<const ushort4*>(
        kvb16 + ((long long)(b * S_ + s0 + sl)) * CR_ + c0 + c4);
    st[sl][c4] = v.x; st[sl][c4+1] = v.y; st[sl][c4+2] = v.z; st[sl][c4+3] = v.w;
    __syncthreads();
    int cl = t >> 3, s4 = (t & 7) * 4;
    ushort4 o;
    o.x = st[s4][cl]; o.y = st[s4+1][cl]; o.z = st[s4+2][cl]; o.w = st[s4+3][cl];
    *reinterpret_cast<ushort4*>(
        vT16 + ((long long)b * 512 + c0 + cl) * 2048 + s0 + s4) = o;
}

// ---------- MFMA flash attention: 8 waves, QB=128, wave-local P, 1 barrier/iter (R7) ----------
__global__ __launch_bounds__(512, 2) void attn_mfma_k(
    const ushort_t* __restrict__ qcat,   // [H][BS][576] bf16
    const ushort_t* __restrict__ kvb16,  // [BS][576] bf16
    const ushort_t* __restrict__ vT16,   // [B][512][2048] bf16
    ushort_t* __restrict__ outc)         // [BS][H*512] bf16
{
    __shared__ ushort_t sKV[2 * 32 * 576];   // XOR-swizzled 16B chunks (low3 ^ row)
    __shared__ ushort_t sVT[2 * 512 * 32];   // line-pair chunk-XOR swizzle

    const int tid = threadIdx.x;
    const int w   = tid >> 6;          // 0..7
    const int ln  = tid & 63;
    const int g   = ln >> 4;
    const int r16 = ln & 15;
    const int bh = blockIdx.y;
    const int b = bh >> 4, h = bh & 15;
    const int s0 = blockIdx.x * 128;

    // staging source offsets (inverse-swizzled), 512-thread partition
    int kvoff[4], kvoff4 = 0;
    #pragma unroll
    for (int i = 0; i < 4; ++i) {
        int p = i * 512 + tid;          // 16B-chunk 0..2047
        int row = p / 72, cs = p - row * 72;
        kvoff[i] = row * 576 + ((cs & ~7) | ((cs ^ row) & 7)) * 8;
    }
    if (w < 4) {
        int p = 2048 + tid;             // chunk 2048..2303
        int row = p / 72, cs = p - row * 72;
        kvoff4 = row * 576 + ((cs & ~7) | ((cs ^ row) & 7)) * 8;
    }
    int vtoff[4];
    #pragma unroll
    for (int i = 0; i < 4; ++i) {
        int p = i * 512 + tid;          // chunk 0..2047
        int rp = p >> 3, sw = p & 7;
        int lg = sw ^ (rp & 7);
        vtoff[i] = (2 * rp + (lg >> 2)) * 2048 + (lg & 3) * 8;
    }

    // Q fragments (B-operand: col=l&15=q-row, k=8g+j); wave w owns q rows s0+16w..+15
    bf16x8 qfrag[18];
    {
        const ushort_t* qp = qcat
            + ((long long)h * BS_ + (long long)b * S_ + (s0 + 16 * w + r16)) * 576 + 8 * g;
        #pragma unroll
        for (int kt = 0; kt < 18; ++kt)
            qfrag[kt] = *reinterpret_cast<const bf16x8*>(qp + 32 * kt);
    }

    const f32x4 zero4 = {0.f, 0.f, 0.f, 0.f};
    f32x4 acc[32];                      // out^T[c=16ct+4g+reg][q=own r16]
    #pragma unroll
    for (int i = 0; i < 32; ++i) acc[i] = zero4;

    float m_run = -1e30f, l_run = 0.0f;
    const float scale = 0.0721687836487032f;  // 192^-0.5

    const ushort_t* kvsrc = kvb16 + (long long)b * S_ * 576;
    const ushort_t* vtsrc = vT16 + (long long)b * 512 * 2048;
    char* skvb = (char*)sKV;
    char* svtb = (char*)sVT;

#define STAGE_TILE(T0, DB) do { \
        const ushort_t* kvt_ = kvsrc + (long long)(T0) * 576; \
        const ushort_t* vtt_ = vtsrc + (T0); \
        _Pragma("unroll") \
        for (int i_ = 0; i_ < 4; ++i_) \
            GLD16(kvt_ + kvoff[i_], skvb + (DB) * 36864 + i_ * 8192 + w * 1024); \
        if (w < 4) GLD16(kvt_ + kvoff4, skvb + (DB) * 36864 + 32768 + w * 1024); \
        _Pragma("unroll") \
        for (int i_ = 0; i_ < 4; ++i_) \
            GLD16(vtt_ + vtoff[i_], svtb + (DB) * 32768 + i_ * 8192 + w * 1024); \
    } while (0)

    STAGE_TILE(0, 0);   // prologue

    for (int t = 0; t < 64; ++t) {
        const int cur = t & 1;
        asm volatile("s_waitcnt vmcnt(0)" ::: "memory");   // own share of tile t landed
        __builtin_amdgcn_s_barrier();                       // all shares landed; bufs free
        __builtin_amdgcn_sched_barrier(0);
        if (t < 63) STAGE_TILE((t + 1) * 32, cur ^ 1);

        // scores^T = mfma(A=KV rows, B=Q): 4 chains of 9
        const int kvb = cur * 18432;
        f32x4 d0a = zero4, d0b = zero4, d1a = zero4, d1b = zero4;
        __builtin_amdgcn_s_setprio(1);
        #pragma unroll
        for (int kt = 0; kt < 9; ++kt) {
            int ch = kt * 4 + g;
            int chs = (ch & ~7) | ((ch ^ r16) & 7);
            bf16x8 a0 = *reinterpret_cast<const bf16x8*>(&sKV[kvb + r16 * 576 + chs * 8]);
            bf16x8 a1 = *reinterpret_cast<const bf16x8*>(&sKV[kvb + (16 + r16) * 576 + chs * 8]);
            d0a = __builtin_amdgcn_mfma_f32_16x16x32_bf16(a0, qfrag[kt], d0a, 0, 0, 0);
            d1a = __builtin_amdgcn_mfma_f32_16x16x32_bf16(a1, qfrag[kt], d1a, 0, 0, 0);
        }
        #pragma unroll
        for (int kt = 9; kt < 18; ++kt) {
            int ch = kt * 4 + g;
            int chs = (ch & ~7) | ((ch ^ r16) & 7);
            bf16x8 a0 = *reinterpret_cast<const bf16x8*>(&sKV[kvb + r16 * 576 + chs * 8]);
            bf16x8 a1 = *reinterpret_cast<const bf16x8*>(&sKV[kvb + (16 + r16) * 576 + chs * 8]);
            d0b = __builtin_amdgcn_mfma_f32_16x16x32_bf16(a0, qfrag[kt], d0b, 0, 0, 0);
            d1b = __builtin_amdgcn_mfma_f32_16x16x32_bf16(a1, qfrag[kt], d1b, 0, 0, 0);
        }
        __builtin_amdgcn_s_setprio(0);
        f32x4 d0 = d0a + d0b, d1 = d1a + d1b;

        // lane-local online softmax (lane owns q-row 16w+r16; t spread over 4 g-groups)
        float p[8];
        #pragma unroll
        for (int i = 0; i < 4; ++i) { p[i] = d0[i] * scale; p[4 + i] = d1[i] * scale; }
        float mt = p[0];
        #pragma unroll
        for (int i = 1; i < 8; ++i) mt = fmaxf(mt, p[i]);
        mt = fmaxf(mt, __shfl_xor(mt, 16, 64));
        mt = fmaxf(mt, __shfl_xor(mt, 32, 64));
        bool anyneed = __any(mt > m_run + 8.0f);   // defer-max THR=8 (wave-local)
        float m_new = anyneed ? fmaxf(m_run, mt) : m_run;
        float fac = anyneed ? __expf(m_run - m_new) : 1.0f;
        m_run = m_new;
        float lt = 0.f;
        #pragma unroll
        for (int i = 0; i < 8; ++i) { p[i] = __expf(p[i] - m_new); lt += p[i]; }
        lt += __shfl_xor(lt, 16, 64);
        lt += __shfl_xor(lt, 32, 64);
        l_run = l_run * fac + lt;

        // P -> bf16 words: w0=(t:4g,4g+1) w1=(4g+2,4g+3) w2=(16+4g,16+4g+1) w3=(16+4g+2,+3)
        uint_t w0, w1, w2, w3;
        asm("v_cvt_pk_bf16_f32 %0, %1, %2" : "=v"(w0) : "v"(p[0]), "v"(p[1]));
        asm("v_cvt_pk_bf16_f32 %0, %1, %2" : "=v"(w1) : "v"(p[2]), "v"(p[3]));
        asm("v_cvt_pk_bf16_f32 %0, %1, %2" : "=v"(w2) : "v"(p[4]), "v"(p[5]));
        asm("v_cvt_pk_bf16_f32 %0, %1, %2" : "=v"(w3) : "v"(p[6]), "v"(p[7]));
        // redistribute: lane group g' needs t = 8g'..8g'+7 for its own q-col r16
        uint_t xa = (uint_t)__shfl_xor((int)((g & 1) ? w0 : w2), 16, 64);
        uint_t xb = (uint_t)__shfl_xor((int)((g & 1) ? w1 : w3), 16, 64);
        uint_t ya = (uint_t)__shfl_xor((int)((g >> 1) ? w0 : w2), 32, 64);
        uint_t yb = (uint_t)__shfl_xor((int)((g >> 1) ? w1 : w3), 32, 64);
        uint_t za = (uint_t)__shfl_xor((int)((g == 1) ? w2 : w0), 48, 64);
        uint_t zb = (uint_t)__shfl_xor((int)((g == 1) ? w3 : w1), 48, 64);
        uint_t pw[4];
        if      (g == 0) { pw[0] = w0; pw[1] = w1; pw[2] = xa; pw[3] = xb; }
        else if (g == 1) { pw[0] = za; pw[1] = zb; pw[2] = ya; pw[3] = yb; }
        else if (g == 2) { pw[0] = ya; pw[1] = yb; pw[2] = za; pw[3] = zb; }
        else             { pw[0] = xa; pw[1] = xb; pw[2] = w2; pw[3] = w3; }
        bf16x8 pB = *reinterpret_cast<bf16x8*>(pw);

        // rescale own acc (fac is lane-local: col q = r16)
        if (anyneed) {
            #pragma unroll
            for (int ct = 0; ct < 32; ++ct) {
                acc[ct][0] *= fac; acc[ct][1] *= fac;
                acc[ct][2] *= fac; acc[ct][3] *= fac;
            }
        }
        // PV: out^T = mfma(A=V^T rows, B=own P); all 512 c rows, own 16 q cols
        const int vtb = cur * 16384;
        __builtin_amdgcn_s_setprio(1);
        #pragma unroll
        for (int ct = 0; ct < 32; ++ct) {
            int c = 16 * ct + r16;
            int sw = ((c & 1) * 4 + g) ^ ((c >> 1) & 7);
            bf16x8 aV = *reinterpret_cast<const bf16x8*>(&sVT[vtb + (c >> 1) * 64 + sw * 8]);
            acc[ct] = __builtin_amdgcn_mfma_f32_16x16x32_bf16(aV, pB, acc[ct], 0, 0, 0);
        }
        __builtin_amdgcn_s_setprio(0);
    }
#undef STAGE_TILE

    // finalize: everything lane-local
    float inv = 1.0f / l_run;
    long long row = (long long)b * S_ + s0 + 16 * w + r16;
    ushort_t* obase = outc + row * 8192 + h * 512;
    #pragma unroll
    for (int ct = 0; ct < 32; ++ct) {
        int cg = 16 * ct + 4 * g;
        ushort4 o;
        o.x = f2us(acc[ct][0] * inv);
        o.y = f2us(acc[ct][1] * inv);
        o.z = f2us(acc[ct][2] * inv);
        o.w = f2us(acc[ct][3] * inv);
        *reinterpret_cast<ushort4*>(obase + cg) = o;
    }
}

// ---------- workspace layout (bytes), total 221,773,824 ----------
extern "C" void kernel_launch(void* const* d_in, const int* in_sizes, int n_in,
                              void* d_out, int out_size, void* d_ws, size_t ws_size,
                              hipStream_t stream)
{
    if (ws_size < 221773824ULL) return;
    const float* x    = (const float*)d_in[0];
    const float* fc   = (const float*)d_in[1];
    const float* fs   = (const float*)d_in[2];
    const float* wq   = (const float*)d_in[3];
    const float* wkva = (const float*)d_in[4];
    const float* wkvb = (const float*)d_in[5];
    const float* wo   = (const float*)d_in[6];
    float* out = (float*)d_out;

    char* ws = (char*)d_ws;
    ushort_t* qcat  = (ushort_t*)(ws);
    ushort_t* outc  = (ushort_t*)(ws + 75497472);
    ushort_t* qb16  = (ushort_t*)(ws + 142606336);
    ushort_t* xb    = (ushort_t*)(ws + 167772160);
    ushort_t* aoutb = (ushort_t*)(ws + 167772160);   // alias xb (dead by step 8)
    ushort_t* wqb   = (ushort_t*)(ws + 184549376);
    ushort_t* kvb16 = (ushort_t*)(ws + 184549376);   // alias wqb (dead after gemm12)
    ushort_t* vT16  = (ushort_t*)(ws + 189267968);   // alias wqb tail
    float*    kvbuf = (float*)(ws + 197132288);
    ushort_t* wob   = (ushort_t*)(ws + 206569472);
    ushort_t* wkvab = (ushort_t*)(ws + 214958080);
    ushort_t* wnTb  = (ushort_t*)(ws + 217579520);
    ushort_t* wvb   = (ushort_t*)(ws + 219676672);

    // 0) all conversions + wnT transpose in one launch
    conv_all_k<<<dim3(21760), 256, 0, stream>>>(
        x, xb, wq, wqb, wo, wob, wkva, wkvab, wkvb, wvb, wnTb);
    // 1+2) q-proj + kv-proj fused
    gemm12_k<<<dim3(29, 32), 256, 0, stream>>>(xb, wqb, wkvab, qb16, kvbuf);
    // 3+4) rope q_pe + (rmsnorm c & rope k_pe) fused
    ropekv_k<<<dim3(8192 + BS_), 256, 0, stream>>>(qb16, qcat, kvbuf, kvb16, fc, fs);
    // 5) transpose -> vT16
    vtrans_k<<<dim3(S_ / 32, C_ / 32, B_), 256, 0, stream>>>(kvb16, vT16);
    // 6) q_abs[h] = q_nope[h] @ wnT[h]^T -> qcat c-part (z=16)
    gemm_mfma_k<ushort_t, false><<<dim3(4, 32, 16), 256, 0, stream>>>(
        qb16, 3072, 192, wnTb, 128, 65536, qcat, 576, (long long)BS_ * 576, NOPE_, 512);
    // 7) MFMA attention (8-wave QB=128, wave-local P, 1 barrier/iter) -> outc
    attn_mfma_k<<<dim3(S_ / 128, B_ * H_), 512, 0, stream>>>(qcat, kvb16, vT16, outc);
    // 8) out_v[h] = out_c[h] @ w_v[h]^T -> aoutb bf16 (z=16)
    gemm_mfma_k<ushort_t, false><<<dim3(1, 32, 16), 256, 0, stream>>>(
        outc, 8192, 512, wvb, 512, 65536, aoutb, 2048, 128, C_, 128);
    // 9) final = aout @ wo^T -> f32 out
    gemm_mfma_k<float, false><<<dim3(16, 32, 1), 256, 0, stream>>>(
        aoutb, 2048, 0, wob, 2048, 0, out, D_, 0, 2048, 2048);
}